// Round 3
// baseline (915.629 us; speedup 1.0000x reference)
//
#include <hip/hip_runtime.h>

typedef unsigned int uint;
typedef unsigned short ushort;
typedef float f32x4 __attribute__((ext_vector_type(4)));
typedef uint u32x4 __attribute__((ext_vector_type(4)));
typedef uint u32x2 __attribute__((ext_vector_type(2)));
typedef __bf16 bf16x8 __attribute__((ext_vector_type(8)));

// Problem constants (fixed by setup_inputs)
constexpr int NR = 150000;   // nodes
constexpr int CD = 256;      // classes == feature dim
constexpr int LR = 50000;    // labeled rows (arange(N) < L)
constexpr int KEX = 56;      // 256 - k(=200): # smallest to exclude per row
constexpr int NB1 = 49984;   // 64-aligned base covering unlabeled span
constexpr int NUP = 100032;  // padded span [NB1, NB1+NUP) ⊇ [LR, NR), 1563*64
constexpr int NTP = 150080;  // padded X^T row count (2345 * 64)

__device__ __forceinline__ ushort f2bf(float x) {
  uint u = __builtin_bit_cast(uint, x);
  u += 0x7FFFu + ((u >> 16) & 1u);   // RNE
  return (ushort)(u >> 16);
}
__device__ __forceinline__ uint key16(uint b) {
  // monotonic bf16-bits -> uint16 key (ascending float order)
  return (b & 0x8000u) ? (~b & 0xFFFFu) : (b | 0x8000u);
}

// ---------------------------------------------------------------------------
// K1: wave-per-row one-hot detection + LDS histograms. 1024 blocks.
// v3: 4-row unroll -> 4 outstanding 1KB row loads per wave (MLP), instead of
// one dependent HBM latency per row.
__global__ __launch_bounds__(256) void k_cls(const float* __restrict__ labels,
                                             int* __restrict__ cls,
                                             float* __restrict__ ca,
                                             float* __restrict__ cl) {
  __shared__ int ha[256], hl[256];
  int t = threadIdx.x;
  ha[t] = 0; hl[t] = 0;
  __syncthreads();
  int lane = t & 63;
  int wid = (blockIdx.x << 2) | (t >> 6);
  int nw = gridDim.x << 2;
  int n = wid;
  for (; n + 3 * nw < NR; n += 4 * nw) {
    f32x4 v[4];
#pragma unroll
    for (int u = 0; u < 4; ++u)
      v[u] = *reinterpret_cast<const f32x4*>(&labels[(size_t)(n + u * nw) * CD + lane * 4]);
#pragma unroll
    for (int u = 0; u < 4; ++u) {
      int nn = n + u * nw;
      int j = v[u][0] > 0.5f ? 0 : v[u][1] > 0.5f ? 1 : v[u][2] > 0.5f ? 2
                                                      : v[u][3] > 0.5f ? 3 : -1;
      if (j >= 0) {
        int c = lane * 4 + j;
        cls[nn] = c;
        atomicAdd(&ha[c], 1);
        if (nn < LR) atomicAdd(&hl[c], 1);
      }
    }
  }
  for (; n < NR; n += nw) {
    f32x4 v = *reinterpret_cast<const f32x4*>(&labels[(size_t)n * CD + lane * 4]);
    int j = v[0] > 0.5f ? 0 : v[1] > 0.5f ? 1 : v[2] > 0.5f ? 2 : v[3] > 0.5f ? 3 : -1;
    if (j >= 0) {
      int c = lane * 4 + j;
      cls[n] = c;
      atomicAdd(&ha[c], 1);
      if (n < LR) atomicAdd(&hl[c], 1);
    }
  }
  __syncthreads();
  atomicAdd(&ca[t], (float)ha[t]);
  atomicAdd(&cl[t], (float)hl[t]);
}

// ---------------------------------------------------------------------------
// K2: per-row invnorm + X^T bf16 in block-panel layout [nblk][256f][64n].
__global__ __launch_bounds__(256) void k_prep(const float* __restrict__ X,
                                              ushort* __restrict__ Xt,
                                              float* __restrict__ invn) {
  __shared__ __align__(16) ushort xl[64 * 264];  // [row][f], +8 pad
  __shared__ float red[256];
  int t = threadIdx.x;
  int r = t >> 2, cq = t & 3;
  int g0 = blockIdx.x * 64;
  int g = g0 + r;
  bool valid = g < NR;
  float ss = 0.f;
#pragma unroll
  for (int j = 0; j < 16; ++j) {
    int col = cq * 4 + j * 16;
    f32x4 x = valid ? *reinterpret_cast<const f32x4*>(&X[g * CD + col])
                    : (f32x4){0.f, 0.f, 0.f, 0.f};
    ss += x[0] * x[0] + x[1] * x[1] + x[2] * x[2] + x[3] * x[3];
    uint p0 = (uint)f2bf(x[0]) | ((uint)f2bf(x[1]) << 16);
    uint p1 = (uint)f2bf(x[2]) | ((uint)f2bf(x[3]) << 16);
    *reinterpret_cast<u32x2*>(&xl[r * 264 + col]) = (u32x2){p0, p1};
  }
  red[t] = ss;
  __syncthreads();
  if (t < 64) {
    float s4 = red[t * 4] + red[t * 4 + 1] + red[t * 4 + 2] + red[t * 4 + 3];
    if (g0 + t < NR) invn[g0 + t] = rsqrtf(fmaxf(s4, 1e-12f));
  }
  // phase 2: panel write — block writes contiguous 32KB: Xt[blk][f][n]
  ushort* xp = Xt + (size_t)blockIdx.x * 16384;
  int f = t;
  uint buf[4];
  for (int n = 0; n < 64; ++n) {
    ushort v16 = xl[n * 264 + f];
    int sl = n & 7;
    if (sl & 1) buf[sl >> 1] |= (uint)v16 << 16; else buf[sl >> 1] = v16;
    if (sl == 7)
      *reinterpret_cast<u32x4*>(&xp[f * 64 + n - 7]) =
          (u32x4){buf[0], buf[1], buf[2], buf[3]};
  }
}

// ---------------------------------------------------------------------------
// Split-K GEMM: OUT[c][f] (+)= sum_n A[n][c] * X[n][f], OUT 256x256.
// KIND 0: A = one-hot labels from cls (rows [0,LR)); KIND 1: A = p^T panels.
// Per-block partial slices (no global atomics). Panel layout [blk][256][64].
template <int KIND>
__global__ __launch_bounds__(1024) void k_gemmB(const int* __restrict__ cls,
                                                const ushort* __restrict__ Ap,
                                                const ushort* __restrict__ Xt,
                                                float* __restrict__ P,
                                                int nch, int nbase) {
  __shared__ __align__(16) ushort Al[256 * 40];  // [c][n-chunk], +8 pad
  __shared__ __align__(16) ushort Bl[256 * 40];  // [f][n-chunk], +8 pad
  int t = threadIdx.x;
  int lane = t & 63, w = t >> 6;
  int m = lane & 15, qd = lane >> 4;
  int cR = t >> 2, off = (t & 3) * 8;
  f32x4 acc[16];
#pragma unroll
  for (int i = 0; i < 16; ++i) acc[i] = (f32x4){0.f, 0.f, 0.f, 0.f};

  if (KIND == 0) {
    for (int i = t; i < 5120; i += 1024) reinterpret_cast<uint*>(Al)[i] = 0u;
  }

  u32x4 aR, bR;
  int curc = -1, prevc = -1;
  int ch = blockIdx.x;
  if (ch < nch) {  // prologue prefetch
    int n0 = ch * 32;
    if (KIND == 1) {
      const ushort* ap = Ap + (size_t)(n0 >> 6) * 16384 + (n0 & 63);
      aR = *reinterpret_cast<const u32x4*>(&ap[cR * 64 + off]);
    } else if (t < 32) {
      int gg = n0 + t;
      curc = (gg < LR) ? cls[gg] : -1;
    }
    int gr = nbase + n0;
    const ushort* xp = Xt + (size_t)(gr >> 6) * 16384 + (gr & 63);
    bR = *reinterpret_cast<const u32x4*>(&xp[cR * 64 + off]);
  }

  for (; ch < nch; ch += gridDim.x) {
    __syncthreads();  // prev MFMA reads done (first iter: zero-fill visible)
    if (KIND == 0) {
      if (t < 32) {
        if (prevc >= 0) Al[prevc * 40 + t] = 0;
        if (curc >= 0) Al[curc * 40 + t] = 0x3F80;  // bf16 1.0
        prevc = curc;
      }
    } else {
      *reinterpret_cast<u32x4*>(&Al[cR * 40 + off]) = aR;
    }
    *reinterpret_cast<u32x4*>(&Bl[cR * 40 + off]) = bR;
    int chn = ch + gridDim.x;
    if (chn < nch) {  // prefetch next chunk; latency hidden under MFMA phase
      int n0 = chn * 32;
      if (KIND == 1) {
        const ushort* ap = Ap + (size_t)(n0 >> 6) * 16384 + (n0 & 63);
        aR = *reinterpret_cast<const u32x4*>(&ap[cR * 64 + off]);
      } else if (t < 32) {
        int gg = n0 + t;
        curc = (gg < LR) ? cls[gg] : -1;
      }
      int gr = nbase + n0;
      const ushort* xp = Xt + (size_t)(gr >> 6) * 16384 + (gr & 63);
      bR = *reinterpret_cast<const u32x4*>(&xp[cR * 64 + off]);
    }
    __syncthreads();
    bf16x8 a = *reinterpret_cast<const bf16x8*>(&Al[(w * 16 + m) * 40 + qd * 8]);
#pragma unroll
    for (int ft = 0; ft < 16; ++ft) {
      bf16x8 b = *reinterpret_cast<const bf16x8*>(&Bl[(ft * 16 + m) * 40 + qd * 8]);
      acc[ft] = __builtin_amdgcn_mfma_f32_16x16x32_bf16(a, b, acc[ft], 0, 0, 0);
    }
  }
  float* Ps = P + (size_t)blockIdx.x * 65536;
#pragma unroll
  for (int ft = 0; ft < 16; ++ft)
#pragma unroll
    for (int r = 0; r < 4; ++r)
      Ps[(w * 16 + qd * 4 + r) * 256 + ft * 16 + m] = acc[ft][r];
}

// ---------------------------------------------------------------------------
// K_protos: reduce partial slices, protos = total/count, normalize -> phat bf16
__global__ __launch_bounds__(256) void k_protos(const float* __restrict__ P, int nsl,
                                                const float* __restrict__ ca,
                                                float* __restrict__ protos,
                                                ushort* __restrict__ phat) {
  __shared__ float red[256];
  int c = blockIdx.x, f = threadIdx.x;
  float s = 0.f;
  for (int i = 0; i < nsl; ++i) s += P[i * 65536 + c * 256 + f];
  float cnt = ca[c];
  float pv = cnt > 0.5f ? s / cnt : 0.f;
  protos[c * 256 + f] = pv;
  red[f] = pv * pv;
  __syncthreads();
  for (int st = 128; st > 0; st >>= 1) {
    if (f < st) red[f] += red[f + st];
    __syncthreads();
  }
  float iv = rsqrtf(fmaxf(red[0], 1e-12f));
  phat[c * 256 + f] = f2bf(pv * iv);
}

// K_update: S reduce + proto update + normalize -> phat2 bf16
__global__ __launch_bounds__(256) void k_update(const float* __restrict__ PS, int nsl,
                                                const float* __restrict__ protos,
                                                const float* __restrict__ q,
                                                const float* __restrict__ clab,
                                                ushort* __restrict__ phat2) {
  __shared__ float red[256];
  int c = blockIdx.x, f = threadIdx.x;
  float s = 0.f;
  for (int i = 0; i < nsl; ++i) s += PS[i * 65536 + c * 256 + f];
  float qc = q[c];
  float den = qc + clab[c];
  float pv = protos[c * 256 + f];
  float np = pv + (s - qc * pv) / den;
  red[f] = np * np;
  __syncthreads();
  for (int st = 128; st > 0; st >>= 1) {
    if (f < st) red[f] += red[f + st];
    __syncthreads();
  }
  float iv = rsqrtf(fmaxf(red[0], 1e-12f));
  phat2[c * 256 + f] = f2bf(np * iv);
}

// ---------------------------------------------------------------------------
// Row GEMM: s[n][c] = l2n(X)[n] . phat[c].  64 rows/block, 4 waves x 16 rows.
// v3: BARRIER-FREE GEMM. A-fragments are per-wave private (wave w only needs
// rows w*16..w*16+15): each lane loads its 8 floats of X directly, scales by
// invn, packs to bf16 in registers. B-fragments load directly from the
// L2-resident 128KB phat. No Al/Bl staging, no syncthreads in the K loop ->
// loads stay in flight across chunks, waves free-run.
// TOPK=1: s16 + bisection are per-wave private too; ONE barrier total
// (before phase 3, which reads cross-wave rows/tkey).
// TOPK=0: zero barriers, zero LDS.
template <int TOPK>
__global__ __launch_bounds__(256, 4) void k_passA(const float* __restrict__ X,
                                                  const float* __restrict__ invn,
                                                  const ushort* __restrict__ Bm,
                                                  float* __restrict__ out,
                                                  ushort* __restrict__ pt,
                                                  float* __restrict__ q,
                                                  int gbase) {
  __shared__ __align__(16) char smem[TOPK ? 35072 : 16];
  int t = threadIdx.x;
  int lane = t & 63, w = t >> 6;
  int m = lane & 15, qd = lane >> 4;
  int g0 = gbase + blockIdx.x * 64;
  int g2 = g0 + w * 16 + m;        // this lane's A row
  bool v2 = g2 < NR;
  float inv2 = v2 ? invn[g2] : 0.f;
  const float* xp = X + (size_t)(v2 ? g2 : 0) * CD + qd * 8;
  const ushort* bp = Bm + m * 256 + qd * 8;
  f32x4 acc[16];
#pragma unroll
  for (int i = 0; i < 16; ++i) acc[i] = (f32x4){0.f, 0.f, 0.f, 0.f};

  // prologue: chunk-0 A in registers
  f32x4 x0 = *reinterpret_cast<const f32x4*>(&xp[0]);
  f32x4 x1 = *reinterpret_cast<const f32x4*>(&xp[4]);

  for (int k0 = 0; k0 < 256; k0 += 32) {
    f32x4 y0 = x0 * inv2, y1 = x1 * inv2;
    uint u0 = (uint)f2bf(y0[0]) | ((uint)f2bf(y0[1]) << 16);
    uint u1 = (uint)f2bf(y0[2]) | ((uint)f2bf(y0[3]) << 16);
    uint u2 = (uint)f2bf(y1[0]) | ((uint)f2bf(y1[1]) << 16);
    uint u3 = (uint)f2bf(y1[2]) | ((uint)f2bf(y1[3]) << 16);
    u32x4 au = (u32x4){u0, u1, u2, u3};
    bf16x8 a = __builtin_bit_cast(bf16x8, au);
    if (k0 < 224) {  // prefetch next A chunk; resolves under the MFMAs
      x0 = *reinterpret_cast<const f32x4*>(&xp[k0 + 32]);
      x1 = *reinterpret_cast<const f32x4*>(&xp[k0 + 36]);
    }
#pragma unroll
    for (int ft = 0; ft < 16; ++ft) {
      u32x4 bu = *reinterpret_cast<const u32x4*>(&bp[ft * 4096 + k0]);
      bf16x8 b = __builtin_bit_cast(bf16x8, bu);
      acc[ft] = __builtin_amdgcn_mfma_f32_16x16x32_bf16(a, b, acc[ft], 0, 0, 0);
    }
  }

  if constexpr (TOPK == 0) {
#pragma unroll
    for (int ft = 0; ft < 16; ++ft)
#pragma unroll
      for (int r = 0; r < 4; ++r) {
        int rr = w * 16 + qd * 4 + r;
        int gg = g0 + rr;
        if (gg < NR) out[gg * 256 + ft * 16 + m] = acc[ft][r];
      }
  } else {
    ushort* s16 = reinterpret_cast<ushort*>(smem);
    uint* tkey = reinterpret_cast<uint*>(smem + 34816);
    // per-wave private s16 rows: no barrier needed before/within bisection
#pragma unroll
    for (int ft = 0; ft < 16; ++ft)
#pragma unroll
      for (int r = 0; r < 4; ++r)
        s16[(w * 16 + qd * 4 + r) * 272 + ft * 16 + m] = f2bf(acc[ft][r]);
    // phase 2: per row, 57th-smallest via 16-step bit-bisection on bf16 keys.
    // 4 rows' chains interleaved -> 4-way ILP on the serial cmp/ballot chain.
    for (int i0 = 0; i0 < 16; i0 += 4) {
      uint kk[4][4];
      uint mth[4];
#pragma unroll
      for (int rr = 0; rr < 4; ++rr) {
        int rw = w * 16 + i0 + rr;
        u32x2 pk = *reinterpret_cast<const u32x2*>(&s16[rw * 272 + lane * 4]);
        kk[rr][0] = key16(pk[0] & 0xFFFFu);
        kk[rr][1] = key16(pk[0] >> 16);
        kk[rr][2] = key16(pk[1] & 0xFFFFu);
        kk[rr][3] = key16(pk[1] >> 16);
        mth[rr] = 0u;
      }
      for (int b = 15; b >= 0; --b) {
#pragma unroll
        for (int rr = 0; rr < 4; ++rr) {
          uint cand = mth[rr] | (1u << b);
          int cnt = __builtin_popcountll(__ballot(kk[rr][0] < cand)) +
                    __builtin_popcountll(__ballot(kk[rr][1] < cand)) +
                    __builtin_popcountll(__ballot(kk[rr][2] < cand)) +
                    __builtin_popcountll(__ballot(kk[rr][3] < cand));
          if (cnt <= KEX) mth[rr] = cand;
        }
      }
      if (lane == 0) {
#pragma unroll
        for (int rr = 0; rr < 4; ++rr) tkey[w * 16 + i0 + rr] = mth[rr];
      }
    }
    __syncthreads();  // the ONE barrier: phase 3 reads all rows + tkey
    // phase 3: thread t owns class c=t; threshold + um mask, q partial,
    // p^T panel write (contiguous 32KB per block)
    int c = t;
    float qloc = 0.f;
    uint buf[4];
    ushort* pp = pt + (size_t)blockIdx.x * 16384;
    for (int n = 0; n < 64; ++n) {
      int grow = g0 + n;
      ushort v16 = s16[n * 272 + c];
      bool keep = (key16(v16) >= tkey[n]) && (grow >= LR) && (grow < NR);
      ushort pv16 = keep ? v16 : (ushort)0;
      if (keep) qloc += __builtin_bit_cast(float, (uint)v16 << 16);
      int sl = n & 7;
      if (sl & 1) buf[sl >> 1] |= (uint)pv16 << 16; else buf[sl >> 1] = pv16;
      if (sl == 7)
        *reinterpret_cast<u32x4*>(&pp[c * 64 + n - 7]) =
            (u32x4){buf[0], buf[1], buf[2], buf[3]};
    }
    atomicAdd(&q[c], qloc);
  }
}

// ---------------------------------------------------------------------------
extern "C" void kernel_launch(void* const* d_in, const int* in_sizes, int n_in,
                              void* d_out, int out_size, void* d_ws, size_t ws_size,
                              hipStream_t stream) {
  const float* inputs = (const float*)d_in[0];
  const float* labels = (const float*)d_in[1];
  float* out = (float*)d_out;

  // d_out doubles as scratch before the final GEMM overwrites it:
  ushort* p_t = (ushort*)d_out;                                  // panels, 51.2 MB
  ushort* Xt  = (ushort*)((char*)d_out + (size_t)256 * NUP * 2); // panels, 76.8 MB

  char* ws = (char*)d_ws;
  float* q      = (float*)(ws + 0);
  float* c_all  = (float*)(ws + 1024);
  float* c_lab  = (float*)(ws + 2048);
  float* protos = (float*)(ws + 4096);
  ushort* phat  = (ushort*)(ws + 4096 + 262144);
  ushort* phat2 = (ushort*)(ws + 4096 + 262144 + 131072);
  float* invn   = (float*)(ws + 528384);
  int*   cls    = (int*)(ws + 1128384);
  size_t base = 1736704;
  int sT = 128, sS = 256;  // partial-slice counts for the two split-K GEMMs
  while (base + (size_t)(sT + sS) * 262144ULL > ws_size) {
    if (sS > sT) sS >>= 1; else if (sT > 8) sT >>= 1; else break;
  }
  float* PT = (float*)(ws + base);
  float* PS = PT + (size_t)sT * 65536;

  hipMemsetAsync(ws, 0, 3072, stream);  // q + counts

  k_cls<<<1024, 256, 0, stream>>>(labels, cls, c_all, c_lab);
  k_prep<<<NTP / 64, 256, 0, stream>>>(inputs, Xt, invn);
  k_gemmB<0><<<sT, 1024, 0, stream>>>(cls, nullptr, Xt, PT, 1563, 0);        // total
  k_protos<<<256, 256, 0, stream>>>(PT, sT, c_all, protos, phat);
  k_passA<1><<<NUP / 64, 256, 0, stream>>>(inputs, invn, phat, nullptr, p_t, q, NB1);
  k_gemmB<1><<<sS, 1024, 0, stream>>>(nullptr, p_t, Xt, PS, NUP / 32, NB1);  // S
  k_update<<<256, 256, 0, stream>>>(PS, sS, protos, q, c_lab, phat2);
  k_passA<0><<<(NR + 63) / 64, 256, 0, stream>>>(inputs, invn, phat2, out, nullptr, nullptr, 0);
}

// Round 4
// 753.686 us; speedup vs baseline: 1.2149x; 1.2149x over previous
//
#include <hip/hip_runtime.h>

typedef unsigned int uint;
typedef unsigned short ushort;
typedef float f32x4 __attribute__((ext_vector_type(4)));
typedef uint u32x4 __attribute__((ext_vector_type(4)));
typedef uint u32x2 __attribute__((ext_vector_type(2)));
typedef __bf16 bf16x8 __attribute__((ext_vector_type(8)));

// Problem constants (fixed by setup_inputs)
constexpr int NR = 150000;   // nodes
constexpr int CD = 256;      // classes == feature dim
constexpr int LR = 50000;    // labeled rows (arange(N) < L)
constexpr int KEX = 56;      // 256 - k(=200): # smallest to exclude per row
constexpr int NB1 = 49984;   // 64-aligned base covering unlabeled span
constexpr int NUP = 100032;  // padded span [NB1, NB1+NUP) ⊇ [LR, NR), 1563*64
constexpr int NTP = 150080;  // padded X^T row count (2345 * 64)

__device__ __forceinline__ ushort f2bf(float x) {
  uint u = __builtin_bit_cast(uint, x);
  u += 0x7FFFu + ((u >> 16) & 1u);   // RNE
  return (ushort)(u >> 16);
}
__device__ __forceinline__ uint key16(uint b) {
  // monotonic bf16-bits -> uint16 key (ascending float order)
  return (b & 0x8000u) ? (~b & 0xFFFFu) : (b | 0x8000u);
}

// ---------------------------------------------------------------------------
// K1: wave-per-row one-hot detection + LDS histograms. 1024 blocks.
// 4-row unroll -> 4 outstanding 1KB row loads per wave (MLP).
__global__ __launch_bounds__(256) void k_cls(const float* __restrict__ labels,
                                             int* __restrict__ cls,
                                             float* __restrict__ ca,
                                             float* __restrict__ cl) {
  __shared__ int ha[256], hl[256];
  int t = threadIdx.x;
  ha[t] = 0; hl[t] = 0;
  __syncthreads();
  int lane = t & 63;
  int wid = (blockIdx.x << 2) | (t >> 6);
  int nw = gridDim.x << 2;
  int n = wid;
  for (; n + 3 * nw < NR; n += 4 * nw) {
    f32x4 v[4];
#pragma unroll
    for (int u = 0; u < 4; ++u)
      v[u] = *reinterpret_cast<const f32x4*>(&labels[(size_t)(n + u * nw) * CD + lane * 4]);
#pragma unroll
    for (int u = 0; u < 4; ++u) {
      int nn = n + u * nw;
      int j = v[u][0] > 0.5f ? 0 : v[u][1] > 0.5f ? 1 : v[u][2] > 0.5f ? 2
                                                      : v[u][3] > 0.5f ? 3 : -1;
      if (j >= 0) {
        int c = lane * 4 + j;
        cls[nn] = c;
        atomicAdd(&ha[c], 1);
        if (nn < LR) atomicAdd(&hl[c], 1);
      }
    }
  }
  for (; n < NR; n += nw) {
    f32x4 v = *reinterpret_cast<const f32x4*>(&labels[(size_t)n * CD + lane * 4]);
    int j = v[0] > 0.5f ? 0 : v[1] > 0.5f ? 1 : v[2] > 0.5f ? 2 : v[3] > 0.5f ? 3 : -1;
    if (j >= 0) {
      int c = lane * 4 + j;
      cls[n] = c;
      atomicAdd(&ha[c], 1);
      if (n < LR) atomicAdd(&hl[c], 1);
    }
  }
  __syncthreads();
  atomicAdd(&ca[t], (float)ha[t]);
  atomicAdd(&cl[t], (float)hl[t]);
}

// ---------------------------------------------------------------------------
// K2: per-row invnorm + X^T bf16 in block-panel layout [nblk][256f][64n].
__global__ __launch_bounds__(256) void k_prep(const float* __restrict__ X,
                                              ushort* __restrict__ Xt,
                                              float* __restrict__ invn) {
  __shared__ __align__(16) ushort xl[64 * 264];  // [row][f], +8 pad
  __shared__ float red[256];
  int t = threadIdx.x;
  int r = t >> 2, cq = t & 3;
  int g0 = blockIdx.x * 64;
  int g = g0 + r;
  bool valid = g < NR;
  float ss = 0.f;
#pragma unroll
  for (int j = 0; j < 16; ++j) {
    int col = cq * 4 + j * 16;
    f32x4 x = valid ? *reinterpret_cast<const f32x4*>(&X[g * CD + col])
                    : (f32x4){0.f, 0.f, 0.f, 0.f};
    ss += x[0] * x[0] + x[1] * x[1] + x[2] * x[2] + x[3] * x[3];
    uint p0 = (uint)f2bf(x[0]) | ((uint)f2bf(x[1]) << 16);
    uint p1 = (uint)f2bf(x[2]) | ((uint)f2bf(x[3]) << 16);
    *reinterpret_cast<u32x2*>(&xl[r * 264 + col]) = (u32x2){p0, p1};
  }
  red[t] = ss;
  __syncthreads();
  if (t < 64) {
    float s4 = red[t * 4] + red[t * 4 + 1] + red[t * 4 + 2] + red[t * 4 + 3];
    if (g0 + t < NR) invn[g0 + t] = rsqrtf(fmaxf(s4, 1e-12f));
  }
  // phase 2: panel write — block writes contiguous 32KB: Xt[blk][f][n]
  ushort* xp = Xt + (size_t)blockIdx.x * 16384;
  int f = t;
  uint buf[4];
  for (int n = 0; n < 64; ++n) {
    ushort v16 = xl[n * 264 + f];
    int sl = n & 7;
    if (sl & 1) buf[sl >> 1] |= (uint)v16 << 16; else buf[sl >> 1] = v16;
    if (sl == 7)
      *reinterpret_cast<u32x4*>(&xp[f * 64 + n - 7]) =
          (u32x4){buf[0], buf[1], buf[2], buf[3]};
  }
}

// ---------------------------------------------------------------------------
// Split-K GEMM: OUT[c][f] (+)= sum_n A[n][c] * X[n][f], OUT 256x256.
// KIND 0: A = one-hot labels from cls (rows [0,LR)); KIND 1: A = p^T panels.
// Per-block partial slices (no global atomics). Panel layout [blk][256][64].
template <int KIND>
__global__ __launch_bounds__(1024) void k_gemmB(const int* __restrict__ cls,
                                                const ushort* __restrict__ Ap,
                                                const ushort* __restrict__ Xt,
                                                float* __restrict__ P,
                                                int nch, int nbase) {
  __shared__ __align__(16) ushort Al[256 * 40];  // [c][n-chunk], +8 pad
  __shared__ __align__(16) ushort Bl[256 * 40];  // [f][n-chunk], +8 pad
  int t = threadIdx.x;
  int lane = t & 63, w = t >> 6;
  int m = lane & 15, qd = lane >> 4;
  int cR = t >> 2, off = (t & 3) * 8;
  f32x4 acc[16];
#pragma unroll
  for (int i = 0; i < 16; ++i) acc[i] = (f32x4){0.f, 0.f, 0.f, 0.f};

  if (KIND == 0) {
    for (int i = t; i < 5120; i += 1024) reinterpret_cast<uint*>(Al)[i] = 0u;
  }

  u32x4 aR, bR;
  int curc = -1, prevc = -1;
  int ch = blockIdx.x;
  if (ch < nch) {  // prologue prefetch
    int n0 = ch * 32;
    if (KIND == 1) {
      const ushort* ap = Ap + (size_t)(n0 >> 6) * 16384 + (n0 & 63);
      aR = *reinterpret_cast<const u32x4*>(&ap[cR * 64 + off]);
    } else if (t < 32) {
      int gg = n0 + t;
      curc = (gg < LR) ? cls[gg] : -1;
    }
    int gr = nbase + n0;
    const ushort* xp = Xt + (size_t)(gr >> 6) * 16384 + (gr & 63);
    bR = *reinterpret_cast<const u32x4*>(&xp[cR * 64 + off]);
  }

  for (; ch < nch; ch += gridDim.x) {
    __syncthreads();  // prev MFMA reads done (first iter: zero-fill visible)
    if (KIND == 0) {
      if (t < 32) {
        if (prevc >= 0) Al[prevc * 40 + t] = 0;
        if (curc >= 0) Al[curc * 40 + t] = 0x3F80;  // bf16 1.0
        prevc = curc;
      }
    } else {
      *reinterpret_cast<u32x4*>(&Al[cR * 40 + off]) = aR;
    }
    *reinterpret_cast<u32x4*>(&Bl[cR * 40 + off]) = bR;
    int chn = ch + gridDim.x;
    if (chn < nch) {  // prefetch next chunk; latency hidden under MFMA phase
      int n0 = chn * 32;
      if (KIND == 1) {
        const ushort* ap = Ap + (size_t)(n0 >> 6) * 16384 + (n0 & 63);
        aR = *reinterpret_cast<const u32x4*>(&ap[cR * 64 + off]);
      } else if (t < 32) {
        int gg = n0 + t;
        curc = (gg < LR) ? cls[gg] : -1;
      }
      int gr = nbase + n0;
      const ushort* xp = Xt + (size_t)(gr >> 6) * 16384 + (gr & 63);
      bR = *reinterpret_cast<const u32x4*>(&xp[cR * 64 + off]);
    }
    __syncthreads();
    bf16x8 a = *reinterpret_cast<const bf16x8*>(&Al[(w * 16 + m) * 40 + qd * 8]);
#pragma unroll
    for (int ft = 0; ft < 16; ++ft) {
      bf16x8 b = *reinterpret_cast<const bf16x8*>(&Bl[(ft * 16 + m) * 40 + qd * 8]);
      acc[ft] = __builtin_amdgcn_mfma_f32_16x16x32_bf16(a, b, acc[ft], 0, 0, 0);
    }
  }
  float* Ps = P + (size_t)blockIdx.x * 65536;
#pragma unroll
  for (int ft = 0; ft < 16; ++ft)
#pragma unroll
    for (int r = 0; r < 4; ++r)
      Ps[(w * 16 + qd * 4 + r) * 256 + ft * 16 + m] = acc[ft][r];
}

// ---------------------------------------------------------------------------
// K_protos: reduce partial slices, protos = total/count, normalize -> phat bf16
__global__ __launch_bounds__(256) void k_protos(const float* __restrict__ P, int nsl,
                                                const float* __restrict__ ca,
                                                float* __restrict__ protos,
                                                ushort* __restrict__ phat) {
  __shared__ float red[256];
  int c = blockIdx.x, f = threadIdx.x;
  float s = 0.f;
  for (int i = 0; i < nsl; ++i) s += P[i * 65536 + c * 256 + f];
  float cnt = ca[c];
  float pv = cnt > 0.5f ? s / cnt : 0.f;
  protos[c * 256 + f] = pv;
  red[f] = pv * pv;
  __syncthreads();
  for (int st = 128; st > 0; st >>= 1) {
    if (f < st) red[f] += red[f + st];
    __syncthreads();
  }
  float iv = rsqrtf(fmaxf(red[0], 1e-12f));
  phat[c * 256 + f] = f2bf(pv * iv);
}

// K_update: S reduce + proto update + normalize -> phat2 bf16
__global__ __launch_bounds__(256) void k_update(const float* __restrict__ PS, int nsl,
                                                const float* __restrict__ protos,
                                                const float* __restrict__ q,
                                                const float* __restrict__ clab,
                                                ushort* __restrict__ phat2) {
  __shared__ float red[256];
  int c = blockIdx.x, f = threadIdx.x;
  float s = 0.f;
  for (int i = 0; i < nsl; ++i) s += PS[i * 65536 + c * 256 + f];
  float qc = q[c];
  float den = qc + clab[c];
  float pv = protos[c * 256 + f];
  float np = pv + (s - qc * pv) / den;
  red[f] = np * np;
  __syncthreads();
  for (int st = 128; st > 0; st >>= 1) {
    if (f < st) red[f] += red[f + st];
    __syncthreads();
  }
  float iv = rsqrtf(fmaxf(red[0], 1e-12f));
  phat2[c * 256 + f] = f2bf(np * iv);
}

// ---------------------------------------------------------------------------
// Row GEMM: s[n][c] = l2n(X)[n] . phat[c].  64 rows/block, 4 waves x 16 rows.
// v4 hybrid: A per-lane in REGISTERS (v3-verified mapping: lane(w,m,qd) loads
// X[g0+w*16+m][qd*8 + k0 ..], scales, packs bf16 — no Al stage, no Al barrier
// dependency). B staged in LDS (v2-verified: 4-wave amortization, short-latency
// ds_read) with register prefetch one chunk ahead. 2 barriers/chunk.
// TOPK=1: s16 aliases Bl (disjoint lifetime, barrier before overwrite);
// bisection per-wave-private; ONE barrier before phase 3.
// TOPK=0: LDS = 20480B only -> occupancy VGPR-capped, not LDS-capped.
template <int TOPK>
__global__ __launch_bounds__(256, 4) void k_passA(const float* __restrict__ X,
                                                  const float* __restrict__ invn,
                                                  const ushort* __restrict__ Bm,
                                                  float* __restrict__ out,
                                                  ushort* __restrict__ pt,
                                                  float* __restrict__ q,
                                                  int gbase) {
  // Bl 20480B live during GEMM; TOPK=1: s16 (34816B)+tkey (256B) alias after.
  __shared__ __align__(16) char smem[TOPK ? 35072 : 20480];
  ushort* Bl = reinterpret_cast<ushort*>(smem);
  int t = threadIdx.x;
  int lane = t & 63, w = t >> 6;
  int m = lane & 15, qd = lane >> 4;
  int g0 = gbase + blockIdx.x * 64;
  int g2 = g0 + w * 16 + m;        // this lane's A row
  bool vA = g2 < NR;
  float inv2 = vA ? invn[g2] : 0.f;
  const float* xp = X + (size_t)(vA ? g2 : 0) * CD + qd * 8;
  int cB = t >> 2, offB = (t & 3) * 8;   // B staging coords
  f32x4 acc[16];
#pragma unroll
  for (int i = 0; i < 16; ++i) acc[i] = (f32x4){0.f, 0.f, 0.f, 0.f};

  // prologue: chunk-0 A (regs) + B (regs, to be staged)
  f32x4 x0 = *reinterpret_cast<const f32x4*>(&xp[0]);
  f32x4 x1 = *reinterpret_cast<const f32x4*>(&xp[4]);
  u32x4 bR[4];
#pragma unroll
  for (int i = 0; i < 4; ++i)
    bR[i] = *reinterpret_cast<const u32x4*>(&Bm[(cB + i * 64) * 256 + offB]);

  for (int k0 = 0; k0 < 256; k0 += 32) {
    // pack current A fragment from regs (overlaps barrier wait)
    f32x4 y0 = x0 * inv2, y1 = x1 * inv2;
    uint u0 = (uint)f2bf(y0[0]) | ((uint)f2bf(y0[1]) << 16);
    uint u1 = (uint)f2bf(y0[2]) | ((uint)f2bf(y0[3]) << 16);
    uint u2 = (uint)f2bf(y1[0]) | ((uint)f2bf(y1[1]) << 16);
    uint u3 = (uint)f2bf(y1[2]) | ((uint)f2bf(y1[3]) << 16);
    u32x4 au = (u32x4){u0, u1, u2, u3};
    bf16x8 a = __builtin_bit_cast(bf16x8, au);
    __syncthreads();  // prev MFMA reads of Bl done
#pragma unroll
    for (int i = 0; i < 4; ++i)
      *reinterpret_cast<u32x4*>(&Bl[(cB + i * 64) * 40 + offB]) = bR[i];
    if (k0 < 224) {  // prefetch next chunk; resolves under the MFMA phase
      int kn = k0 + 32;
      x0 = *reinterpret_cast<const f32x4*>(&xp[kn]);
      x1 = *reinterpret_cast<const f32x4*>(&xp[kn + 4]);
#pragma unroll
      for (int i = 0; i < 4; ++i)
        bR[i] = *reinterpret_cast<const u32x4*>(
            &Bm[(cB + i * 64) * 256 + kn + offB]);
    }
    __syncthreads();
#pragma unroll
    for (int ft = 0; ft < 16; ++ft) {
      bf16x8 b = *reinterpret_cast<const bf16x8*>(&Bl[(ft * 16 + m) * 40 + qd * 8]);
      acc[ft] = __builtin_amdgcn_mfma_f32_16x16x32_bf16(a, b, acc[ft], 0, 0, 0);
    }
  }

  if constexpr (TOPK == 0) {
#pragma unroll
    for (int ft = 0; ft < 16; ++ft)
#pragma unroll
      for (int r = 0; r < 4; ++r) {
        int rr = w * 16 + qd * 4 + r;
        int gg = g0 + rr;
        if (gg < NR) out[gg * 256 + ft * 16 + m] = acc[ft][r];
      }
  } else {
    ushort* s16 = reinterpret_cast<ushort*>(smem);          // aliases Bl
    uint* tkey = reinterpret_cast<uint*>(smem + 34816);
    __syncthreads();  // all waves' MFMA reads of Bl complete before overwrite
#pragma unroll
    for (int ft = 0; ft < 16; ++ft)
#pragma unroll
      for (int r = 0; r < 4; ++r)
        s16[(w * 16 + qd * 4 + r) * 272 + ft * 16 + m] = f2bf(acc[ft][r]);
    // phase 2: per row, 57th-smallest via 16-step bit-bisection on bf16 keys.
    // Rows are per-wave private (own wave wrote them): no barrier needed.
    // 4 rows' chains interleaved -> 4-way ILP on the serial cmp/ballot chain.
    for (int i0 = 0; i0 < 16; i0 += 4) {
      uint kk[4][4];
      uint mth[4];
#pragma unroll
      for (int rr = 0; rr < 4; ++rr) {
        int rw = w * 16 + i0 + rr;
        u32x2 pk = *reinterpret_cast<const u32x2*>(&s16[rw * 272 + lane * 4]);
        kk[rr][0] = key16(pk[0] & 0xFFFFu);
        kk[rr][1] = key16(pk[0] >> 16);
        kk[rr][2] = key16(pk[1] & 0xFFFFu);
        kk[rr][3] = key16(pk[1] >> 16);
        mth[rr] = 0u;
      }
      for (int b = 15; b >= 0; --b) {
#pragma unroll
        for (int rr = 0; rr < 4; ++rr) {
          uint cand = mth[rr] | (1u << b);
          int cnt = __builtin_popcountll(__ballot(kk[rr][0] < cand)) +
                    __builtin_popcountll(__ballot(kk[rr][1] < cand)) +
                    __builtin_popcountll(__ballot(kk[rr][2] < cand)) +
                    __builtin_popcountll(__ballot(kk[rr][3] < cand));
          if (cnt <= KEX) mth[rr] = cand;
        }
      }
      if (lane == 0) {
#pragma unroll
        for (int rr = 0; rr < 4; ++rr) tkey[w * 16 + i0 + rr] = mth[rr];
      }
    }
    __syncthreads();  // the ONE barrier: phase 3 reads all rows + tkey
    // phase 3: thread t owns class c=t; threshold + um mask, q partial,
    // p^T panel write (contiguous 32KB per block)
    int c = t;
    float qloc = 0.f;
    uint buf[4];
    ushort* pp = pt + (size_t)blockIdx.x * 16384;
    for (int n = 0; n < 64; ++n) {
      int grow = g0 + n;
      ushort v16 = s16[n * 272 + c];
      bool keep = (key16(v16) >= tkey[n]) && (grow >= LR) && (grow < NR);
      ushort pv16 = keep ? v16 : (ushort)0;
      if (keep) qloc += __builtin_bit_cast(float, (uint)v16 << 16);
      int sl = n & 7;
      if (sl & 1) buf[sl >> 1] |= (uint)pv16 << 16; else buf[sl >> 1] = pv16;
      if (sl == 7)
        *reinterpret_cast<u32x4*>(&pp[c * 64 + n - 7]) =
            (u32x4){buf[0], buf[1], buf[2], buf[3]};
    }
    atomicAdd(&q[c], qloc);
  }
}

// ---------------------------------------------------------------------------
extern "C" void kernel_launch(void* const* d_in, const int* in_sizes, int n_in,
                              void* d_out, int out_size, void* d_ws, size_t ws_size,
                              hipStream_t stream) {
  const float* inputs = (const float*)d_in[0];
  const float* labels = (const float*)d_in[1];
  float* out = (float*)d_out;

  // d_out doubles as scratch before the final GEMM overwrites it:
  ushort* p_t = (ushort*)d_out;                                  // panels, 51.2 MB
  ushort* Xt  = (ushort*)((char*)d_out + (size_t)256 * NUP * 2); // panels, 76.8 MB

  char* ws = (char*)d_ws;
  float* q      = (float*)(ws + 0);
  float* c_all  = (float*)(ws + 1024);
  float* c_lab  = (float*)(ws + 2048);
  float* protos = (float*)(ws + 4096);
  ushort* phat  = (ushort*)(ws + 4096 + 262144);
  ushort* phat2 = (ushort*)(ws + 4096 + 262144 + 131072);
  float* invn   = (float*)(ws + 528384);
  int*   cls    = (int*)(ws + 1128384);
  size_t base = 1736704;
  int sT = 256, sS = 256;  // partial-slice counts for the two split-K GEMMs
  while (base + (size_t)(sT + sS) * 262144ULL > ws_size) {
    if (sS > sT) sS >>= 1; else if (sT > 8) sT >>= 1; else break;
  }
  float* PT = (float*)(ws + base);
  float* PS = PT + (size_t)sT * 65536;

  hipMemsetAsync(ws, 0, 3072, stream);  // q + counts

  k_cls<<<1024, 256, 0, stream>>>(labels, cls, c_all, c_lab);
  k_prep<<<NTP / 64, 256, 0, stream>>>(inputs, Xt, invn);
  k_gemmB<0><<<sT, 1024, 0, stream>>>(cls, nullptr, Xt, PT, 1563, 0);        // total
  k_protos<<<256, 256, 0, stream>>>(PT, sT, c_all, protos, phat);
  k_passA<1><<<NUP / 64, 256, 0, stream>>>(inputs, invn, phat, nullptr, p_t, q, NB1);
  k_gemmB<1><<<sS, 1024, 0, stream>>>(nullptr, p_t, Xt, PS, NUP / 32, NB1);  // S
  k_update<<<256, 256, 0, stream>>>(PS, sS, protos, q, c_lab, phat2);
  k_passA<0><<<(NR + 63) / 64, 256, 0, stream>>>(inputs, invn, phat2, out, nullptr, nullptr, 0);
}

// Round 5
// 717.876 us; speedup vs baseline: 1.2755x; 1.0499x over previous
//
#include <hip/hip_runtime.h>

typedef unsigned int uint;
typedef unsigned short ushort;
typedef float f32x4 __attribute__((ext_vector_type(4)));
typedef uint u32x4 __attribute__((ext_vector_type(4)));
typedef uint u32x2 __attribute__((ext_vector_type(2)));
typedef __bf16 bf16x8 __attribute__((ext_vector_type(8)));

// Problem constants (fixed by setup_inputs)
constexpr int NR = 150000;   // nodes
constexpr int CD = 256;      // classes == feature dim
constexpr int LR = 50000;    // labeled rows (arange(N) < L)
constexpr int KEX = 56;      // 256 - k(=200): # smallest to exclude per row
constexpr int NB1 = 49984;   // 64-aligned base covering unlabeled span
constexpr int NUP = 100032;  // padded span [NB1, NB1+NUP) ⊇ [LR, NR), 1563*64
constexpr int NTP = 150080;  // padded X^T row count (2345 * 64)
constexpr int NPB = NTP / 64;        // 2345 prep blocks
constexpr int NCB = 1024;            // cls blocks
constexpr int NFB = NPB + NCB;       // 3369 fused blocks

__device__ __forceinline__ ushort f2bf(float x) {
  uint u = __builtin_bit_cast(uint, x);
  u += 0x7FFFu + ((u >> 16) & 1u);   // RNE
  return (ushort)(u >> 16);
}
__device__ __forceinline__ uint key16(uint b) {
  // monotonic bf16-bits -> uint16 key (ascending float order)
  return (b & 0x8000u) ? (~b & 0xFFFFu) : (b | 0x8000u);
}
__device__ __forceinline__ float bfval(uint p) {
  return __builtin_bit_cast(float, p << 16);
}

// ---------------------------------------------------------------------------
// K_pre: fused k_cls + k_prep (independent memory-bound streamers share the
// BW window in one dispatch). Block roles interleaved via Bresenham so cls
// and prep blocks co-run. cls: wave-per-row one-hot detect + histograms.
// prep: per-row invnorm + X^T bf16 block-panel [nblk][256f][64n].
__global__ __launch_bounds__(256) void k_pre(const float* __restrict__ X,
                                             const float* __restrict__ labels,
                                             ushort* __restrict__ Xt,
                                             float* __restrict__ invn,
                                             int* __restrict__ cls,
                                             float* __restrict__ ca,
                                             float* __restrict__ cl) {
  __shared__ __align__(16) char sm[34816];
  int t = threadIdx.x;
  uint bx = blockIdx.x;
  uint ia = (bx * (uint)NCB) / (uint)NFB;
  uint ib = ((bx + 1) * (uint)NCB) / (uint)NFB;
  if (ib > ia) {
    // ---------------- cls role, cid = ia ----------------
    int* ha = (int*)sm;
    int* hl = (int*)(sm + 1024);
    ha[t] = 0; hl[t] = 0;
    __syncthreads();
    int lane = t & 63;
    int wid = ((int)ia << 2) | (t >> 6);
    int nw = NCB << 2;
    int n = wid;
    for (; n + 3 * nw < NR; n += 4 * nw) {
      f32x4 v[4];
#pragma unroll
      for (int u = 0; u < 4; ++u)
        v[u] = *reinterpret_cast<const f32x4*>(&labels[(size_t)(n + u * nw) * CD + lane * 4]);
#pragma unroll
      for (int u = 0; u < 4; ++u) {
        int nn = n + u * nw;
        int j = v[u][0] > 0.5f ? 0 : v[u][1] > 0.5f ? 1 : v[u][2] > 0.5f ? 2
                                                        : v[u][3] > 0.5f ? 3 : -1;
        if (j >= 0) {
          int c = lane * 4 + j;
          cls[nn] = c;
          atomicAdd(&ha[c], 1);
          if (nn < LR) atomicAdd(&hl[c], 1);
        }
      }
    }
    for (; n < NR; n += nw) {
      f32x4 v = *reinterpret_cast<const f32x4*>(&labels[(size_t)n * CD + lane * 4]);
      int j = v[0] > 0.5f ? 0 : v[1] > 0.5f ? 1 : v[2] > 0.5f ? 2 : v[3] > 0.5f ? 3 : -1;
      if (j >= 0) {
        int c = lane * 4 + j;
        cls[n] = c;
        atomicAdd(&ha[c], 1);
        if (n < LR) atomicAdd(&hl[c], 1);
      }
    }
    __syncthreads();
    atomicAdd(&ca[t], (float)ha[t]);
    atomicAdd(&cl[t], (float)hl[t]);
  } else {
    // ---------------- prep role, pb = bx - ia ----------------
    int pb = (int)(bx - ia);
    ushort* xl = (ushort*)sm;              // [64][264], 33792B
    float* red = (float*)(sm + 33792);     // 1024B
    int r = t >> 2, cq = t & 3;
    int g0 = pb * 64;
    int g = g0 + r;
    bool valid = g < NR;
    float ss = 0.f;
#pragma unroll
    for (int j = 0; j < 16; ++j) {
      int col = cq * 4 + j * 16;
      f32x4 x = valid ? *reinterpret_cast<const f32x4*>(&X[g * CD + col])
                      : (f32x4){0.f, 0.f, 0.f, 0.f};
      ss += x[0] * x[0] + x[1] * x[1] + x[2] * x[2] + x[3] * x[3];
      uint p0 = (uint)f2bf(x[0]) | ((uint)f2bf(x[1]) << 16);
      uint p1 = (uint)f2bf(x[2]) | ((uint)f2bf(x[3]) << 16);
      *reinterpret_cast<u32x2*>(&xl[r * 264 + col]) = (u32x2){p0, p1};
    }
    red[t] = ss;
    __syncthreads();
    if (t < 64) {
      float s4 = red[t * 4] + red[t * 4 + 1] + red[t * 4 + 2] + red[t * 4 + 3];
      if (g0 + t < NR) invn[g0 + t] = rsqrtf(fmaxf(s4, 1e-12f));
    }
    // panel write — block writes contiguous 32KB: Xt[blk][f][n]
    ushort* xp = Xt + (size_t)pb * 16384;
    int f = t;
    uint buf[4];
    for (int n = 0; n < 64; ++n) {
      ushort v16 = xl[n * 264 + f];
      int sl = n & 7;
      if (sl & 1) buf[sl >> 1] |= (uint)v16 << 16; else buf[sl >> 1] = v16;
      if (sl == 7)
        *reinterpret_cast<u32x4*>(&xp[f * 64 + n - 7]) =
            (u32x4){buf[0], buf[1], buf[2], buf[3]};
    }
  }
}

// ---------------------------------------------------------------------------
// Split-K GEMM: OUT[c][f] (+)= sum_n A[n][c] * X[n][f], OUT 256x256.
// KIND 0: A = one-hot labels from cls (rows [0,LR)); KIND 1: A = p^T panels.
// Per-block partial slices (no global atomics). Panel layout [blk][256][64].
template <int KIND>
__global__ __launch_bounds__(1024) void k_gemmB(const int* __restrict__ cls,
                                                const ushort* __restrict__ Ap,
                                                const ushort* __restrict__ Xt,
                                                float* __restrict__ P,
                                                int nch, int nbase) {
  __shared__ __align__(16) ushort Al[256 * 40];  // [c][n-chunk], +8 pad
  __shared__ __align__(16) ushort Bl[256 * 40];  // [f][n-chunk], +8 pad
  int t = threadIdx.x;
  int lane = t & 63, w = t >> 6;
  int m = lane & 15, qd = lane >> 4;
  int cR = t >> 2, off = (t & 3) * 8;
  f32x4 acc[16];
#pragma unroll
  for (int i = 0; i < 16; ++i) acc[i] = (f32x4){0.f, 0.f, 0.f, 0.f};

  if (KIND == 0) {
    for (int i = t; i < 5120; i += 1024) reinterpret_cast<uint*>(Al)[i] = 0u;
  }

  u32x4 aR, bR;
  int curc = -1, prevc = -1;
  int ch = blockIdx.x;
  if (ch < nch) {  // prologue prefetch
    int n0 = ch * 32;
    if (KIND == 1) {
      const ushort* ap = Ap + (size_t)(n0 >> 6) * 16384 + (n0 & 63);
      aR = *reinterpret_cast<const u32x4*>(&ap[cR * 64 + off]);
    } else if (t < 32) {
      int gg = n0 + t;
      curc = (gg < LR) ? cls[gg] : -1;
    }
    int gr = nbase + n0;
    const ushort* xp = Xt + (size_t)(gr >> 6) * 16384 + (gr & 63);
    bR = *reinterpret_cast<const u32x4*>(&xp[cR * 64 + off]);
  }

  for (; ch < nch; ch += gridDim.x) {
    __syncthreads();  // prev MFMA reads done (first iter: zero-fill visible)
    if (KIND == 0) {
      if (t < 32) {
        if (prevc >= 0) Al[prevc * 40 + t] = 0;
        if (curc >= 0) Al[curc * 40 + t] = 0x3F80;  // bf16 1.0
        prevc = curc;
      }
    } else {
      *reinterpret_cast<u32x4*>(&Al[cR * 40 + off]) = aR;
    }
    *reinterpret_cast<u32x4*>(&Bl[cR * 40 + off]) = bR;
    int chn = ch + gridDim.x;
    if (chn < nch) {  // prefetch next chunk; latency hidden under MFMA phase
      int n0 = chn * 32;
      if (KIND == 1) {
        const ushort* ap = Ap + (size_t)(n0 >> 6) * 16384 + (n0 & 63);
        aR = *reinterpret_cast<const u32x4*>(&ap[cR * 64 + off]);
      } else if (t < 32) {
        int gg = n0 + t;
        curc = (gg < LR) ? cls[gg] : -1;
      }
      int gr = nbase + n0;
      const ushort* xp = Xt + (size_t)(gr >> 6) * 16384 + (gr & 63);
      bR = *reinterpret_cast<const u32x4*>(&xp[cR * 64 + off]);
    }
    __syncthreads();
    bf16x8 a = *reinterpret_cast<const bf16x8*>(&Al[(w * 16 + m) * 40 + qd * 8]);
#pragma unroll
    for (int ft = 0; ft < 16; ++ft) {
      bf16x8 b = *reinterpret_cast<const bf16x8*>(&Bl[(ft * 16 + m) * 40 + qd * 8]);
      acc[ft] = __builtin_amdgcn_mfma_f32_16x16x32_bf16(a, b, acc[ft], 0, 0, 0);
    }
  }
  float* Ps = P + (size_t)blockIdx.x * 65536;
#pragma unroll
  for (int ft = 0; ft < 16; ++ft)
#pragma unroll
    for (int r = 0; r < 4; ++r)
      Ps[(w * 16 + qd * 4 + r) * 256 + ft * 16 + m] = acc[ft][r];
}

// ---------------------------------------------------------------------------
// K_protos: reduce partial slices, protos = total/count, normalize -> phat bf16
__global__ __launch_bounds__(256) void k_protos(const float* __restrict__ P, int nsl,
                                                const float* __restrict__ ca,
                                                float* __restrict__ protos,
                                                ushort* __restrict__ phat) {
  __shared__ float red[256];
  int c = blockIdx.x, f = threadIdx.x;
  float s = 0.f;
  for (int i = 0; i < nsl; ++i) s += P[i * 65536 + c * 256 + f];
  float cnt = ca[c];
  float pv = cnt > 0.5f ? s / cnt : 0.f;
  protos[c * 256 + f] = pv;
  red[f] = pv * pv;
  __syncthreads();
  for (int st = 128; st > 0; st >>= 1) {
    if (f < st) red[f] += red[f + st];
    __syncthreads();
  }
  float iv = rsqrtf(fmaxf(red[0], 1e-12f));
  phat[c * 256 + f] = f2bf(pv * iv);
}

// K_update: S reduce + proto update + normalize -> phat2 bf16
__global__ __launch_bounds__(256) void k_update(const float* __restrict__ PS, int nsl,
                                                const float* __restrict__ protos,
                                                const float* __restrict__ q,
                                                const float* __restrict__ clab,
                                                ushort* __restrict__ phat2) {
  __shared__ float red[256];
  int c = blockIdx.x, f = threadIdx.x;
  float s = 0.f;
  for (int i = 0; i < nsl; ++i) s += PS[i * 65536 + c * 256 + f];
  float qc = q[c];
  float den = qc + clab[c];
  float pv = protos[c * 256 + f];
  float np = pv + (s - qc * pv) / den;
  red[f] = np * np;
  __syncthreads();
  for (int st = 128; st > 0; st >>= 1) {
    if (f < st) red[f] += red[f + st];
    __syncthreads();
  }
  float iv = rsqrtf(fmaxf(red[0], 1e-12f));
  phat2[c * 256 + f] = f2bf(np * iv);
}

// ---------------------------------------------------------------------------
// Row GEMM: s[n][c] = l2n(X)[n] . phat[c].  64 rows/block, 4 waves x 16 rows.
// A per-lane in registers (verified mapping), B staged in LDS w/ reg prefetch.
// v5 TOPK=1 tail: phase 3 fully in registers — every lane keeps the
// thresholds of its OWN 4 rows from the bisection (grab mth when i0==qd*4;
// all 64 lanes compute identical mth), masks its own acc values, packs bf16
// pairs, swaps with lane^16 partner via shfl_xor, odd-qd lanes emit the 16B
// panel store straight to global. q accumulated via LDS float atomics.
// Removes: 64 serial ds_read_u16/thread, tkey LDS, one barrier.
template <int TOPK>
__global__ __launch_bounds__(256, 4) void k_passA(const float* __restrict__ X,
                                                  const float* __restrict__ invn,
                                                  const ushort* __restrict__ Bm,
                                                  float* __restrict__ out,
                                                  ushort* __restrict__ pt,
                                                  float* __restrict__ q,
                                                  int gbase) {
  // Bl 20480B live during GEMM; TOPK=1: s16 (34816B) aliases after; qlds +1KB.
  __shared__ __align__(16) char smem[TOPK ? 35840 : 20480];
  ushort* Bl = reinterpret_cast<ushort*>(smem);
  float* qlds = reinterpret_cast<float*>(smem + 34816);
  int t = threadIdx.x;
  int lane = t & 63, w = t >> 6;
  int m = lane & 15, qd = lane >> 4;
  int g0 = gbase + blockIdx.x * 64;
  int g2 = g0 + w * 16 + m;        // this lane's A row
  bool vA = g2 < NR;
  float inv2 = vA ? invn[g2] : 0.f;
  const float* xp = X + (size_t)(vA ? g2 : 0) * CD + qd * 8;
  int cB = t >> 2, offB = (t & 3) * 8;   // B staging coords
  if (TOPK) qlds[t] = 0.f;               // ordered by GEMM barriers
  f32x4 acc[16];
#pragma unroll
  for (int i = 0; i < 16; ++i) acc[i] = (f32x4){0.f, 0.f, 0.f, 0.f};

  // prologue: chunk-0 A (regs) + B (regs, to be staged)
  f32x4 x0 = *reinterpret_cast<const f32x4*>(&xp[0]);
  f32x4 x1 = *reinterpret_cast<const f32x4*>(&xp[4]);
  u32x4 bR[4];
#pragma unroll
  for (int i = 0; i < 4; ++i)
    bR[i] = *reinterpret_cast<const u32x4*>(&Bm[(cB + i * 64) * 256 + offB]);

  for (int k0 = 0; k0 < 256; k0 += 32) {
    f32x4 y0 = x0 * inv2, y1 = x1 * inv2;
    uint u0 = (uint)f2bf(y0[0]) | ((uint)f2bf(y0[1]) << 16);
    uint u1 = (uint)f2bf(y0[2]) | ((uint)f2bf(y0[3]) << 16);
    uint u2 = (uint)f2bf(y1[0]) | ((uint)f2bf(y1[1]) << 16);
    uint u3 = (uint)f2bf(y1[2]) | ((uint)f2bf(y1[3]) << 16);
    u32x4 au = (u32x4){u0, u1, u2, u3};
    bf16x8 a = __builtin_bit_cast(bf16x8, au);
    __syncthreads();  // prev MFMA reads of Bl done
#pragma unroll
    for (int i = 0; i < 4; ++i)
      *reinterpret_cast<u32x4*>(&Bl[(cB + i * 64) * 40 + offB]) = bR[i];
    if (k0 < 224) {  // prefetch next chunk; resolves under the MFMA phase
      int kn = k0 + 32;
      x0 = *reinterpret_cast<const f32x4*>(&xp[kn]);
      x1 = *reinterpret_cast<const f32x4*>(&xp[kn + 4]);
#pragma unroll
      for (int i = 0; i < 4; ++i)
        bR[i] = *reinterpret_cast<const u32x4*>(
            &Bm[(cB + i * 64) * 256 + kn + offB]);
    }
    __syncthreads();
#pragma unroll
    for (int ft = 0; ft < 16; ++ft) {
      bf16x8 b = *reinterpret_cast<const bf16x8*>(&Bl[(ft * 16 + m) * 40 + qd * 8]);
      acc[ft] = __builtin_amdgcn_mfma_f32_16x16x32_bf16(a, b, acc[ft], 0, 0, 0);
    }
  }

  if constexpr (TOPK == 0) {
#pragma unroll
    for (int ft = 0; ft < 16; ++ft)
#pragma unroll
      for (int r = 0; r < 4; ++r) {
        int rr = w * 16 + qd * 4 + r;
        int gg = g0 + rr;
        if (gg < NR) out[gg * 256 + ft * 16 + m] = acc[ft][r];
      }
  } else {
    ushort* s16 = reinterpret_cast<ushort*>(smem);          // aliases Bl
    __syncthreads();  // all waves' MFMA reads of Bl complete before overwrite
#pragma unroll
    for (int ft = 0; ft < 16; ++ft)
#pragma unroll
      for (int r = 0; r < 4; ++r)
        s16[(w * 16 + qd * 4 + r) * 272 + ft * 16 + m] = f2bf(acc[ft][r]);
    // phase 2: per row, 57th-smallest via 16-step bit-bisection on bf16 keys.
    // Rows are per-wave private (own wave wrote them): no barrier needed.
    // Lane captures its OWN rows' thresholds when i0 == qd*4.
    uint tk0 = 0, tk1 = 0, tk2 = 0, tk3 = 0;
    for (int i0 = 0; i0 < 16; i0 += 4) {
      uint kk[4][4];
      uint mth[4];
#pragma unroll
      for (int rr = 0; rr < 4; ++rr) {
        int rw = w * 16 + i0 + rr;
        u32x2 pk = *reinterpret_cast<const u32x2*>(&s16[rw * 272 + lane * 4]);
        kk[rr][0] = key16(pk[0] & 0xFFFFu);
        kk[rr][1] = key16(pk[0] >> 16);
        kk[rr][2] = key16(pk[1] & 0xFFFFu);
        kk[rr][3] = key16(pk[1] >> 16);
        mth[rr] = 0u;
      }
      for (int b = 15; b >= 0; --b) {
#pragma unroll
        for (int rr = 0; rr < 4; ++rr) {
          uint cand = mth[rr] | (1u << b);
          int cnt = __builtin_popcountll(__ballot(kk[rr][0] < cand)) +
                    __builtin_popcountll(__ballot(kk[rr][1] < cand)) +
                    __builtin_popcountll(__ballot(kk[rr][2] < cand)) +
                    __builtin_popcountll(__ballot(kk[rr][3] < cand));
          if (cnt <= KEX) mth[rr] = cand;
        }
      }
      if (i0 == (qd << 2)) { tk0 = mth[0]; tk1 = mth[1]; tk2 = mth[2]; tk3 = mth[3]; }
    }
    // phase 3 (registers): mask own values, pair with qd^1 partner, store.
    int brow = g0 + w * 16 + qd * 4;
    bool ok0 = (brow + 0 >= LR) && (brow + 0 < NR);
    bool ok1 = (brow + 1 >= LR) && (brow + 1 < NR);
    bool ok2 = (brow + 2 >= LR) && (brow + 2 < NR);
    bool ok3 = (brow + 3 >= LR) && (brow + 3 < NR);
    ushort* pp = pt + (size_t)blockIdx.x * 16384;
#pragma unroll
    for (int ft = 0; ft < 16; ++ft) {
      uint v0 = f2bf(acc[ft][0]), v1 = f2bf(acc[ft][1]);
      uint v2 = f2bf(acc[ft][2]), v3 = f2bf(acc[ft][3]);
      uint p0 = (ok0 && key16(v0) >= tk0) ? v0 : 0u;
      uint p1 = (ok1 && key16(v1) >= tk1) ? v1 : 0u;
      uint p2 = (ok2 && key16(v2) >= tk2) ? v2 : 0u;
      uint p3 = (ok3 && key16(v3) >= tk3) ? v3 : 0u;
      uint lo = p0 | (p1 << 16), hi = p2 | (p3 << 16);
      float qv = bfval(p0) + bfval(p1) + bfval(p2) + bfval(p3);
      uint plo = __shfl_xor(lo, 16);
      uint phi = __shfl_xor(hi, 16);
      if (qd & 1)
        *reinterpret_cast<u32x4*>(
            &pp[(ft * 16 + m) * 64 + w * 16 + (qd >> 1) * 8]) =
            (u32x4){plo, phi, lo, hi};
      atomicAdd(&qlds[ft * 16 + m], qv);
    }
    __syncthreads();
    atomicAdd(&q[t], qlds[t]);
  }
}

// ---------------------------------------------------------------------------
extern "C" void kernel_launch(void* const* d_in, const int* in_sizes, int n_in,
                              void* d_out, int out_size, void* d_ws, size_t ws_size,
                              hipStream_t stream) {
  const float* inputs = (const float*)d_in[0];
  const float* labels = (const float*)d_in[1];
  float* out = (float*)d_out;

  // d_out doubles as scratch before the final GEMM overwrites it:
  ushort* p_t = (ushort*)d_out;                                  // panels, 51.2 MB
  ushort* Xt  = (ushort*)((char*)d_out + (size_t)256 * NUP * 2); // panels, 76.8 MB

  char* ws = (char*)d_ws;
  float* q      = (float*)(ws + 0);
  float* c_all  = (float*)(ws + 1024);
  float* c_lab  = (float*)(ws + 2048);
  float* protos = (float*)(ws + 4096);
  ushort* phat  = (ushort*)(ws + 4096 + 262144);
  ushort* phat2 = (ushort*)(ws + 4096 + 262144 + 131072);
  float* invn   = (float*)(ws + 528384);
  int*   cls    = (int*)(ws + 1128384);
  size_t base = 1736704;
  int sT = 256, sS = 256;  // partial-slice counts for the two split-K GEMMs
  while (base + (size_t)(sT + sS) * 262144ULL > ws_size) {
    if (sS > sT) sS >>= 1; else if (sT > 8) sT >>= 1; else break;
  }
  float* PT = (float*)(ws + base);
  float* PS = PT + (size_t)sT * 65536;

  hipMemsetAsync(ws, 0, 3072, stream);  // q + counts

  k_pre<<<NFB, 256, 0, stream>>>(inputs, labels, Xt, invn, cls, c_all, c_lab);
  k_gemmB<0><<<sT, 1024, 0, stream>>>(cls, nullptr, Xt, PT, 1563, 0);        // total
  k_protos<<<256, 256, 0, stream>>>(PT, sT, c_all, protos, phat);
  k_passA<1><<<NUP / 64, 256, 0, stream>>>(inputs, invn, phat, nullptr, p_t, q, NB1);
  k_gemmB<1><<<sS, 1024, 0, stream>>>(nullptr, p_t, Xt, PS, NUP / 32, NB1);  // S
  k_update<<<256, 256, 0, stream>>>(PS, sS, protos, q, c_lab, phat2);
  k_passA<0><<<(NR + 63) / 64, 256, 0, stream>>>(inputs, invn, phat2, out, nullptr, nullptr, 0);
}